// Round 8
// baseline (2864.001 us; speedup 1.0000x reference)
//
#include <hip/hip_runtime.h>
#include <math.h>

// GRU_32564442038643 — round 13.
//  R12 post-mortem: 1 wave/SIMD = 1182us, VGPR=244. Root cause identified:
//  MFMA A/B operands must live in v0-v255 (upper 256 of the unified file is
//  accumulator-only) -> 384 regs of weight frags CANNOT be resident; compiler
//  streams weights from L2 per step. R10's 2-wave/SIMD config (810us) streams
//  too, but the partner wave covers the latency -> confirmed local optimum for
//  rec internals.
//  R13: overlap xgemm with rec (serial 150us -> hidden). ONE fused launch,
//  256 WGs: bid 0-15 = rec (R10 body, byte-identical math), bid 16-255 =
//  producer (35 units each, t-ascending). Per-(t,g) flags in ws: producer
//  threadfence+barrier+release-store; rec gates its X prefetch on the flag,
//  flag load issued ONE STEP EARLY (register-carried, zero steady cost;
//  vmcnt(4) = 3 prefetch + 1 flag fresh -> drains exactly last step's loads).
//  Deadlock-free: rec WGs dispatched first, producers never wait. Flags
//  zeroed by pack (stream-ordered). 66KB LDS -> 1 WG/CU -> 256 CUs busy.

#define BATCH  256
#define SEQ    512
#define INPUT  256
#define HIDDEN 256
#define DTOT   512
#define NTC    48     // ntc = 6w+s, s:{0,1}=r,{2,3}=z,{4,5}=c, cols (2w+(s&1))*16..
#define NT_O   16
#define LOG2E  1.44269504088896f
#define NPROD  240

typedef float          f32x4 __attribute__((ext_vector_type(4)));
typedef short          s16x8 __attribute__((ext_vector_type(8)));
typedef unsigned short u16x8 __attribute__((ext_vector_type(8)));
typedef unsigned int   u32x2 __attribute__((ext_vector_type(2)));

// ws layout (bytes)
#define WH_OFF   0u            // 393216: h-part weights, ntc frag order, exp2-scaled bf16
#define WX_OFF   393216u       // 393216: x-part, same order
#define WO_OFF   786432u       // 131072: Wo
#define X_OFF    917504u       // 201326592: X[unit][ntc][lane] u32x2, unit = t*16+g
#define FLAG_OFF (917504u + 201326592u)          // 32768: int flags[8192]
#define WS_NEED_FUSED (917504ull + 201326592ull + 32768ull)
#define WS_NEED_SPLIT (917504ull + 201326592ull)
#define WS_NEED_OLD   786432ull

__device__ __forceinline__ unsigned short f2bf(float f) {        // RNE
    unsigned int u = __float_as_uint(f);
    u += 0x7FFFu + ((u >> 16) & 1u);
    return (unsigned short)(u >> 16);
}
__device__ __forceinline__ float bf2f(unsigned short u) {
    return __uint_as_float(((unsigned int)u) << 16);
}
__device__ __forceinline__ f32x4 cvt4(u32x2 u) {
    f32x4 a;
    a[0] = __uint_as_float(u[0] << 16);
    a[1] = __uint_as_float(u[0] & 0xffff0000u);
    a[2] = __uint_as_float(u[1] << 16);
    a[3] = __uint_as_float(u[1] & 0xffff0000u);
    return a;
}
__device__ __forceinline__ unsigned int pk2bf(float a, float b) {
    return ((__float_as_uint(a) + 0x8000u) >> 16) |
           ((__float_as_uint(b) + 0x8000u) & 0xFFFF0000u);
}
#if __has_builtin(__builtin_amdgcn_exp2f)
#define EXP2F(x) __builtin_amdgcn_exp2f(x)
#else
#define EXP2F(x) exp2f(x)
#endif
#if __has_builtin(__builtin_amdgcn_rcpf)
#define RCPF(x) __builtin_amdgcn_rcpf(x)
#else
#define RCPF(x) (1.0f / (x))
#endif

#define WAITCNT_VM3()   asm volatile("s_waitcnt vmcnt(3)" ::: "memory")
#define WAITCNT_VM4()   asm volatile("s_waitcnt vmcnt(4)" ::: "memory")
#define WAITCNT_LGKM0() asm volatile("s_waitcnt lgkmcnt(0)" ::: "memory")
#define BAR() do { __builtin_amdgcn_s_barrier(); __builtin_amdgcn_sched_barrier(0); } while (0)

__device__ __forceinline__ void async_ld16(const void* g, void* l) {
    __builtin_amdgcn_global_load_lds(
        (const __attribute__((address_space(1))) unsigned int*)g,
        (__attribute__((address_space(3))) unsigned int*)l, 16, 0, 0);
}

// ntc -> (gate, col-base)
__device__ __forceinline__ void ntc_decode(int ntc, int& gate, int& colbase) {
    int w = ntc / 6, s = ntc - 6 * w;
    gate = s >> 1;
    colbase = (2 * w + (s & 1)) * 16;
}

// ---------------- weight packing (+ flag zeroing for the fused path) ---------
__global__ __launch_bounds__(256) void pack_weights_k(
    const float* __restrict__ Wr, const float* __restrict__ Wz,
    const float* __restrict__ Wh, const float* __restrict__ Wo,
    unsigned short* __restrict__ ws, int zflags)
{
    int tid = blockIdx.x * 256 + threadIdx.x;   // 896 tiles * 64
    if (zflags && tid < 4096) {
        u32x2 z; z[0] = 0u; z[1] = 0u;
        ((u32x2*)((char*)ws + FLAG_OFF))[tid] = z;   // 8192 ints zeroed
    }
    int tile = tid >> 6;
    int l = tid & 63, quad = l >> 4, lan = l & 15;
    u16x8 v;
    unsigned short* dst;
    if (tile < 768) {
        int isH = tile < 384;
        int t2 = isH ? tile : tile - 384;       // = ntc*8 + kt
        int ntc = t2 >> 3, kt = t2 & 7;
        int gate, colbase;
        ntc_decode(ntc, gate, colbase);
        const float* W = gate == 0 ? Wr : (gate == 1 ? Wz : Wh);
        float scale = (gate == 2) ? 2.f * LOG2E : LOG2E;
        int col = colbase + lan;
        int kbase = (isH ? 256 : 0) + kt * 32 + quad * 8;
        #pragma unroll
        for (int j = 0; j < 8; ++j) v[j] = f2bf(W[(kbase + j) * 256 + col] * scale);
        dst = (unsigned short*)((char*)ws + (isH ? WH_OFF : WX_OFF)) + (size_t)(t2 * 64 + l) * 8;
    } else {
        int t2 = tile - 768;                    // = kt*16 + nt_o
        int kt = t2 / NT_O, nt = t2 % NT_O;
        int col = nt * 16 + lan;
        int kbase = kt * 32 + quad * 8;
        #pragma unroll
        for (int j = 0; j < 8; ++j) v[j] = f2bf(Wo[(kbase + j) * 256 + col]);
        dst = (unsigned short*)((char*)ws + WO_OFF) + (size_t)(t2 * 64 + l) * 8;
    }
    *(u16x8*)dst = v;
}

// ---------------- fused producer/consumer kernel ----------------
// bid 0..15: rec for batch group b=bid (R10 body + flag gating).
// bid 16..255: producer p=bid-16, units u = p, p+240, ... (t-ascending).
__global__ __launch_bounds__(512, 2) void fused_k(
    const float* __restrict__ x,
    const float* __restrict__ br, const float* __restrict__ bz, const float* __restrict__ bh,
    const float* __restrict__ bo,
    unsigned short* __restrict__ ws,
    float* __restrict__ out)
{
    extern __shared__ __align__(16) char smem[];
    const int bid = blockIdx.x;
    const int th = threadIdx.x, wave = th >> 6, l = th & 63, quad = l >> 4, lan = l & 15;
    int* flags = (int*)((char*)ws + FLAG_OFF);

    if (bid >= 16) {
        // ================= producer (R10 xgemm body, strided units) ==========
        unsigned short (*Xbf)[264] = (unsigned short (*)[264])smem;
        const int p = bid - 16;
        const s16x8* WX = (const s16x8*)((char*)ws + WX_OFF);
        s16x8 wx[6][8];
        #pragma unroll
        for (int fi = 0; fi < 6; ++fi)
            #pragma unroll
            for (int kt = 0; kt < 8; ++kt)
                wx[fi][kt] = WX[(((size_t)(6 * wave + fi)) * 8 + kt) * 64 + l];
        f32x4 bias4[6];
        #pragma unroll
        for (int fi = 0; fi < 6; ++fi) {
            int gate, colbase;
            ntc_decode(6 * wave + fi, gate, colbase);
            const float* bb = gate == 0 ? br : (gate == 1 ? bz : bh);
            f32x4 bv = *(const f32x4*)&bb[colbase + quad * 4];
            float scale = (gate == 2 ? 2.f * LOG2E : LOG2E);
            bias4[fi][0] = bv[0] * scale; bias4[fi][1] = bv[1] * scale;
            bias4[fi][2] = bv[2] * scale; bias4[fi][3] = bv[3] * scale;
        }
        u32x2* Xout = (u32x2*)((char*)ws + X_OFF);

        f32x4 xs[2];
        {   // prime first unit
            int t = p >> 4, gg = p & 15;
            #pragma unroll
            for (int rr = 0; rr < 2; ++rr)
                xs[rr] = *(const f32x4*)(x + (((size_t)(gg * 16 + 2 * wave + rr)) * SEQ + t) * INPUT + l * 4);
        }
        for (int uu = p; uu < SEQ * 16; uu += NPROD) {
            if (uu != p) BAR();                  // prior read phase done
            #pragma unroll
            for (int rr = 0; rr < 2; ++rr) {
                u32x2 pk;
                pk[0] = pk2bf(xs[rr][0], xs[rr][1]);
                pk[1] = pk2bf(xs[rr][2], xs[rr][3]);
                *(u32x2*)&Xbf[2 * wave + rr][l * 4] = pk;
            }
            int un = uu + NPROD;
            if (un < SEQ * 16) {                 // stage next unit into regs
                int t = un >> 4, gg = un & 15;
                #pragma unroll
                for (int rr = 0; rr < 2; ++rr)
                    xs[rr] = *(const f32x4*)(x + (((size_t)(gg * 16 + 2 * wave + rr)) * SEQ + t) * INPUT + l * 4);
            }
            WAITCNT_LGKM0();
            BAR();
            f32x4 acc[6];
            #pragma unroll
            for (int fi = 0; fi < 6; ++fi) acc[fi] = bias4[fi];
            #pragma unroll
            for (int kt = 0; kt < 8; ++kt) {
                s16x8 a = *(const s16x8*)&Xbf[lan][kt * 32 + quad * 8];
                #pragma unroll
                for (int fi = 0; fi < 6; ++fi)
                    acc[fi] = __builtin_amdgcn_mfma_f32_16x16x32_bf16(wx[fi][kt], a, acc[fi], 0, 0, 0);
            }
            #pragma unroll
            for (int fi = 0; fi < 6; ++fi) {
                u32x2 pk;
                pk[0] = pk2bf(acc[fi][0], acc[fi][1]);
                pk[1] = pk2bf(acc[fi][2], acc[fi][3]);
                Xout[((size_t)uu * NTC + 6 * wave + fi) * 64 + l] = pk;
            }
            // publish unit uu: all threads' stores device-visible, then flag
            __threadfence();
            __syncthreads();
            if (th == 0)
                __hip_atomic_store(&flags[uu], 1, __ATOMIC_RELEASE, __HIP_MEMORY_SCOPE_AGENT);
        }
        return;
    }

    // ================= consumer: rec for b = bid (R10 body) ==================
    unsigned short (*Hb)[264]  = (unsigned short (*)[264])smem;
    unsigned short (*RHb)[264] = (unsigned short (*)[264])(smem + 8448);
    char* Xr = smem + 16896;                       // [2][8 waves][3072]
    const int b = bid;
    const s16x8* WH = (const s16x8*)((char*)ws + WH_OFF);
    s16x8 wfr[2][8], wfz[2][8], wfc[2][8];
    #pragma unroll
    for (int i = 0; i < 2; ++i)
        #pragma unroll
        for (int kt = 0; kt < 8; ++kt) {
            wfr[i][kt] = WH[((6 * wave + i) * 8 + kt) * 64 + l];
            wfz[i][kt] = WH[((6 * wave + 2 + i) * 8 + kt) * 64 + l];
            wfc[i][kt] = WH[((6 * wave + 4 + i) * 8 + kt) * 64 + l];
        }
    for (int idx = th; idx < 16 * 264; idx += 512) ((unsigned short*)Hb)[idx] = 0;
    float h[2][4];
    #pragma unroll
    for (int i = 0; i < 2; ++i)
        #pragma unroll
        for (int r = 0; r < 4; ++r) h[i][r] = 0.f;

    const char* Xg = (const char*)ws + X_OFF;
    // gate t=0 slab, then prime prefetch
    while (__hip_atomic_load(&flags[b], __ATOMIC_RELAXED, __HIP_MEMORY_SCOPE_AGENT) == 0) {}
    __builtin_amdgcn_sched_barrier(0);
    {
        const char* sb = Xg + (((size_t)b) * NTC + 6 * wave) * 512;
        char* db = Xr + wave * 3072;
        #pragma unroll
        for (int inst = 0; inst < 3; ++inst)
            async_ld16(sb + inst * 1024 + l * 16, db + inst * 1024);
    }
    int fv = __hip_atomic_load(&flags[16 + b], __ATOMIC_RELAXED, __HIP_MEMORY_SCOPE_AGENT);
    __syncthreads();                               // zero-init + prime visible

    for (int t = 0; t < SEQ; ++t) {
        int buf = t & 1;
        // fv = flags[(t+1)*16+b], loaded one step early; poll only if late
        if (t + 1 < SEQ && fv != 1) {
            do {
                fv = __hip_atomic_load(&flags[(t + 1) * 16 + b], __ATOMIC_RELAXED, __HIP_MEMORY_SCOPE_AGENT);
            } while (fv != 1);
            __builtin_amdgcn_sched_barrier(0);
        }
        {   // prefetch t+1 -> buf^1; rides across both barriers
            int t1 = (t + 1 < SEQ) ? t + 1 : t;
            const char* sb = Xg + (((size_t)(t1 * 16 + b)) * NTC + 6 * wave) * 512;
            char* db = Xr + (buf ^ 1) * 24576 + wave * 3072;
            #pragma unroll
            for (int inst = 0; inst < 3; ++inst)
                async_ld16(sb + inst * 1024 + l * 16, db + inst * 1024);
        }
        // early-issue next flag load (consumed next step; latency hidden)
        fv = (t + 2 < SEQ)
           ? __hip_atomic_load(&flags[(t + 2) * 16 + b], __ATOMIC_RELAXED, __HIP_MEMORY_SCOPE_AGENT)
           : 1;
        WAITCNT_VM4();                             // 3 prefetch + 1 flag fresh; older drained
        const char* Xw = Xr + buf * 24576 + wave * 3072;

        // ---- phase A: r,z preacts (swapped: thread = [lan][4 cols]) ----
        f32x4 ar[2], az[2];
        #pragma unroll
        for (int i = 0; i < 2; ++i) {
            ar[i] = cvt4(*(const u32x2*)(Xw + (size_t)i * 512 + l * 8));
            az[i] = cvt4(*(const u32x2*)(Xw + (size_t)(2 + i) * 512 + l * 8));
        }
        #pragma unroll
        for (int kt = 0; kt < 8; ++kt) {
            s16x8 a = *(const s16x8*)&Hb[lan][kt * 32 + quad * 8];
            #pragma unroll
            for (int i = 0; i < 2; ++i) {
                ar[i] = __builtin_amdgcn_mfma_f32_16x16x32_bf16(wfr[i][kt], a, ar[i], 0, 0, 0);
                az[i] = __builtin_amdgcn_mfma_f32_16x16x32_bf16(wfz[i][kt], a, az[i], 0, 0, 0);
            }
        }
        #pragma unroll
        for (int i = 0; i < 2; ++i) {
            int colb = (2 * wave + i) * 16 + quad * 4;
            float rg0 = RCPF(1.f + EXP2F(-ar[i][0]));
            float rg1 = RCPF(1.f + EXP2F(-ar[i][1]));
            float rg2 = RCPF(1.f + EXP2F(-ar[i][2]));
            float rg3 = RCPF(1.f + EXP2F(-ar[i][3]));
            u32x2 rp;
            rp[0] = pk2bf(rg0 * h[i][0], rg1 * h[i][1]);
            rp[1] = pk2bf(rg2 * h[i][2], rg3 * h[i][3]);
            *(u32x2*)&RHb[lan][colb] = rp;         // one ds_write_b64
        }
        WAITCNT_LGKM0();
        BAR();

        float zg[2][4];
        #pragma unroll
        for (int i = 0; i < 2; ++i)
            #pragma unroll
            for (int r = 0; r < 4; ++r)
                zg[i][r] = RCPF(1.f + EXP2F(-az[i][r]));

        // ---- phase B: candidate ----
        f32x4 ac[2];
        #pragma unroll
        for (int i = 0; i < 2; ++i)
            ac[i] = cvt4(*(const u32x2*)(Xw + (size_t)(4 + i) * 512 + l * 8));
        #pragma unroll
        for (int kt = 0; kt < 8; ++kt) {
            s16x8 a = *(const s16x8*)&RHb[lan][kt * 32 + quad * 8];
            #pragma unroll
            for (int i = 0; i < 2; ++i)
                ac[i] = __builtin_amdgcn_mfma_f32_16x16x32_bf16(wfc[i][kt], a, ac[i], 0, 0, 0);
        }
        #pragma unroll
        for (int i = 0; i < 2; ++i) {
            int colb = (2 * wave + i) * 16 + quad * 4;
            #pragma unroll
            for (int r = 0; r < 4; ++r) {
                float e  = EXP2F(ac[i][r]);              // exp(2*preact)
                float hc = (e - 1.f) * RCPF(e + 1.f);    // tanh
                h[i][r] = zg[i][r] * (h[i][r] - hc) + hc;
            }
            u32x2 hp;
            hp[0] = pk2bf(h[i][0], h[i][1]);
            hp[1] = pk2bf(h[i][2], h[i][3]);
            *(u32x2*)&Hb[lan][colb] = hp;          // one ds_write_b64
        }
        WAITCNT_LGKM0();
        BAR();
    }

    // ---- epilogue: out = h_last @ Wo + bo (swapped; dwordx4 stores) ----
    const s16x8* WO = (const s16x8*)((char*)ws + WO_OFF);
    #pragma unroll
    for (int i = 0; i < 2; ++i) {
        int nt = 2 * wave + i;
        f32x4 acc = *(const f32x4*)&bo[nt * 16 + quad * 4];
        #pragma unroll
        for (int kt = 0; kt < 8; ++kt) {
            s16x8 a = *(const s16x8*)&Hb[lan][kt * 32 + quad * 8];
            acc = __builtin_amdgcn_mfma_f32_16x16x32_bf16(WO[(kt * NT_O + nt) * 64 + l], a, acc, 0, 0, 0);
        }
        *(f32x4*)&out[(size_t)(b * 16 + lan) * 256 + nt * 16 + quad * 4] = acc;
    }
}

// ---------------- split-path fallbacks (R10, verified 810us rec) -------------
__global__ __launch_bounds__(512, 2) void xgemm_k(
    const float* __restrict__ x,
    const float* __restrict__ br, const float* __restrict__ bz, const float* __restrict__ bh,
    unsigned short* __restrict__ ws)
{
    __shared__ __align__(16) unsigned short Xbf[16][264];
    const int th = threadIdx.x, wave = th >> 6, l = th & 63, quad = l >> 4, lan = l & 15;
    const s16x8* WX = (const s16x8*)((char*)ws + WX_OFF);
    s16x8 wx[6][8];
    #pragma unroll
    for (int fi = 0; fi < 6; ++fi)
        #pragma unroll
        for (int kt = 0; kt < 8; ++kt)
            wx[fi][kt] = WX[(((size_t)(6 * wave + fi)) * 8 + kt) * 64 + l];
    f32x4 bias4[6];
    #pragma unroll
    for (int fi = 0; fi < 6; ++fi) {
        int gate, colbase;
        ntc_decode(6 * wave + fi, gate, colbase);
        const float* bb = gate == 0 ? br : (gate == 1 ? bz : bh);
        f32x4 bv = *(const f32x4*)&bb[colbase + quad * 4];
        float scale = (gate == 2 ? 2.f * LOG2E : LOG2E);
        bias4[fi][0] = bv[0] * scale; bias4[fi][1] = bv[1] * scale;
        bias4[fi][2] = bv[2] * scale; bias4[fi][3] = bv[3] * scale;
    }
    u32x2* Xout = (u32x2*)((char*)ws + X_OFF);
    f32x4 xs[2];
    {
        int unit = blockIdx.x * 32, t = unit >> 4, gg = unit & 15;
        #pragma unroll
        for (int rr = 0; rr < 2; ++rr)
            xs[rr] = *(const f32x4*)(x + (((size_t)(gg * 16 + 2 * wave + rr)) * SEQ + t) * INPUT + l * 4);
    }
    for (int uu = 0; uu < 32; ++uu) {
        if (uu > 0) BAR();
        #pragma unroll
        for (int rr = 0; rr < 2; ++rr) {
            u32x2 p;
            p[0] = pk2bf(xs[rr][0], xs[rr][1]);
            p[1] = pk2bf(xs[rr][2], xs[rr][3]);
            *(u32x2*)&Xbf[2 * wave + rr][l * 4] = p;
        }
        if (uu + 1 < 32) {
            int unit = blockIdx.x * 32 + uu + 1, t = unit >> 4, gg = unit & 15;
            #pragma unroll
            for (int rr = 0; rr < 2; ++rr)
                xs[rr] = *(const f32x4*)(x + (((size_t)(gg * 16 + 2 * wave + rr)) * SEQ + t) * INPUT + l * 4);
        }
        WAITCNT_LGKM0();
        BAR();
        f32x4 acc[6];
        #pragma unroll
        for (int fi = 0; fi < 6; ++fi) acc[fi] = bias4[fi];
        #pragma unroll
        for (int kt = 0; kt < 8; ++kt) {
            s16x8 a = *(const s16x8*)&Xbf[lan][kt * 32 + quad * 8];
            #pragma unroll
            for (int fi = 0; fi < 6; ++fi)
                acc[fi] = __builtin_amdgcn_mfma_f32_16x16x32_bf16(wx[fi][kt], a, acc[fi], 0, 0, 0);
        }
        size_t unit = (size_t)blockIdx.x * 32 + uu;
        #pragma unroll
        for (int fi = 0; fi < 6; ++fi) {
            u32x2 p;
            p[0] = pk2bf(acc[fi][0], acc[fi][1]);
            p[1] = pk2bf(acc[fi][2], acc[fi][3]);
            Xout[(unit * NTC + 6 * wave + fi) * 64 + l] = p;
        }
    }
}

__global__ __launch_bounds__(512, 2) void gru_rec_k(
    const float* __restrict__ bo,
    unsigned short* __restrict__ ws,
    float* __restrict__ out)
{
    extern __shared__ __align__(16) char smem[];
    unsigned short (*Hb)[264]  = (unsigned short (*)[264])smem;
    unsigned short (*RHb)[264] = (unsigned short (*)[264])(smem + 8448);
    char* Xr = smem + 16896;

    const int th = threadIdx.x, wave = th >> 6, l = th & 63, quad = l >> 4, lan = l & 15;
    const int b = blockIdx.x;
    const s16x8* WH = (const s16x8*)((char*)ws + WH_OFF);
    s16x8 wfr[2][8], wfz[2][8], wfc[2][8];
    #pragma unroll
    for (int i = 0; i < 2; ++i)
        #pragma unroll
        for (int kt = 0; kt < 8; ++kt) {
            wfr[i][kt] = WH[((6 * wave + i) * 8 + kt) * 64 + l];
            wfz[i][kt] = WH[((6 * wave + 2 + i) * 8 + kt) * 64 + l];
            wfc[i][kt] = WH[((6 * wave + 4 + i) * 8 + kt) * 64 + l];
        }
    for (int idx = th; idx < 16 * 264; idx += 512) ((unsigned short*)Hb)[idx] = 0;
    float h[2][4];
    #pragma unroll
    for (int i = 0; i < 2; ++i)
        #pragma unroll
        for (int r = 0; r < 4; ++r) h[i][r] = 0.f;

    const char* Xg = (const char*)ws + X_OFF;
    {
        const char* sb = Xg + (((size_t)b) * NTC + 6 * wave) * 512;
        char* db = Xr + wave * 3072;
        #pragma unroll
        for (int inst = 0; inst < 3; ++inst)
            async_ld16(sb + inst * 1024 + l * 16, db + inst * 1024);
    }
    __syncthreads();

    for (int t = 0; t < SEQ; ++t) {
        int buf = t & 1;
        {
            int t1 = (t + 1 < SEQ) ? t + 1 : t;
            const char* sb = Xg + (((size_t)(t1 * 16 + b)) * NTC + 6 * wave) * 512;
            char* db = Xr + (buf ^ 1) * 24576 + wave * 3072;
            #pragma unroll
            for (int inst = 0; inst < 3; ++inst)
                async_ld16(sb + inst * 1024 + l * 16, db + inst * 1024);
        }
        WAITCNT_VM3();
        const char* Xw = Xr + buf * 24576 + wave * 3072;

        f32x4 ar[2], az[2];
        #pragma unroll
        for (int i = 0; i < 2; ++i) {
            ar[i] = cvt4(*(const u32x2*)(Xw + (size_t)i * 512 + l * 8));
            az[i] = cvt4(*(const u32x2*)(Xw + (size_t)(2 + i) * 512 + l * 8));
        }
        #pragma unroll
        for (int kt = 0; kt < 8; ++kt) {
            s16x8 a = *(const s16x8*)&Hb[lan][kt * 32 + quad * 8];
            #pragma unroll
            for (int i = 0; i < 2; ++i) {
                ar[i] = __builtin_amdgcn_mfma_f32_16x16x32_bf16(wfr[i][kt], a, ar[i], 0, 0, 0);
                az[i] = __builtin_amdgcn_mfma_f32_16x16x32_bf16(wfz[i][kt], a, az[i], 0, 0, 0);
            }
        }
        #pragma unroll
        for (int i = 0; i < 2; ++i) {
            int colb = (2 * wave + i) * 16 + quad * 4;
            float rg0 = RCPF(1.f + EXP2F(-ar[i][0]));
            float rg1 = RCPF(1.f + EXP2F(-ar[i][1]));
            float rg2 = RCPF(1.f + EXP2F(-ar[i][2]));
            float rg3 = RCPF(1.f + EXP2F(-ar[i][3]));
            u32x2 rp;
            rp[0] = pk2bf(rg0 * h[i][0], rg1 * h[i][1]);
            rp[1] = pk2bf(rg2 * h[i][2], rg3 * h[i][3]);
            *(u32x2*)&RHb[lan][colb] = rp;
        }
        WAITCNT_LGKM0();
        BAR();

        float zg[2][4];
        #pragma unroll
        for (int i = 0; i < 2; ++i)
            #pragma unroll
            for (int r = 0; r < 4; ++r)
                zg[i][r] = RCPF(1.f + EXP2F(-az[i][r]));

        f32x4 ac[2];
        #pragma unroll
        for (int i = 0; i < 2; ++i)
            ac[i] = cvt4(*(const u32x2*)(Xw + (size_t)(4 + i) * 512 + l * 8));
        #pragma unroll
        for (int kt = 0; kt < 8; ++kt) {
            s16x8 a = *(const s16x8*)&RHb[lan][kt * 32 + quad * 8];
            #pragma unroll
            for (int i = 0; i < 2; ++i)
                ac[i] = __builtin_amdgcn_mfma_f32_16x16x32_bf16(wfc[i][kt], a, ac[i], 0, 0, 0);
        }
        #pragma unroll
        for (int i = 0; i < 2; ++i) {
            int colb = (2 * wave + i) * 16 + quad * 4;
            #pragma unroll
            for (int r = 0; r < 4; ++r) {
                float e  = EXP2F(ac[i][r]);
                float hc = (e - 1.f) * RCPF(e + 1.f);
                h[i][r] = zg[i][r] * (h[i][r] - hc) + hc;
            }
            u32x2 hp;
            hp[0] = pk2bf(h[i][0], h[i][1]);
            hp[1] = pk2bf(h[i][2], h[i][3]);
            *(u32x2*)&Hb[lan][colb] = hp;
        }
        WAITCNT_LGKM0();
        BAR();
    }

    const s16x8* WO = (const s16x8*)((char*)ws + WO_OFF);
    #pragma unroll
    for (int i = 0; i < 2; ++i) {
        int nt = 2 * wave + i;
        f32x4 acc = *(const f32x4*)&bo[nt * 16 + quad * 4];
        #pragma unroll
        for (int kt = 0; kt < 8; ++kt) {
            s16x8 a = *(const s16x8*)&Hb[lan][kt * 32 + quad * 8];
            acc = __builtin_amdgcn_mfma_f32_16x16x32_bf16(WO[(kt * NT_O + nt) * 64 + l], a, acc, 0, 0, 0);
        }
        *(f32x4*)&out[(size_t)(b * 16 + lan) * 256 + nt * 16 + quad * 4] = acc;
    }
}

// ---------------- simple fallbacks (ws too small) ----------------
__global__ __launch_bounds__(256) void prep_weights_k(
    const float* __restrict__ Wr, const float* __restrict__ Wz,
    const float* __restrict__ Wh, unsigned short* __restrict__ W16)
{
    const int n = DTOT * HIDDEN;
    int idx = blockIdx.x * 256 + threadIdx.x;
    if (idx >= 3 * n) return;
    int m = idx / n;
    int r = idx - m * n;
    const float* src = (m == 0) ? Wr : ((m == 1) ? Wz : Wh);
    W16[idx] = f2bf(src[r]);
}
__device__ __forceinline__ float ldw(const unsigned short* p) { return bf2f(*p); }
__device__ __forceinline__ float ldw(const float* p)          { return *p; }

template <typename WT>
__global__ __launch_bounds__(256) void gru_seq_k(
    const float* __restrict__ x,
    const WT* __restrict__ Wr, const WT* __restrict__ Wz, const WT* __restrict__ Wh,
    const float* __restrict__ br, const float* __restrict__ bz, const float* __restrict__ bh,
    const float* __restrict__ Wo, const float* __restrict__ bo,
    float* __restrict__ out)
{
    const int b = blockIdx.x, j = threadIdx.x;
    __shared__ float xh[DTOT];
    __shared__ float xrh[DTOT];
    xh[INPUT + j] = 0.0f;
    const float brj = br[j], bzj = bz[j], bhj = bh[j];
    const float* xb = x + (size_t)b * SEQ * INPUT;
    const WT* wrj = Wr + j;
    const WT* wzj = Wz + j;
    const WT* whj = Wh + j;
    __syncthreads();
    for (int t = 0; t < SEQ; ++t) {
        float xv = xb[t * INPUT + j];
        xh[j] = xv; xrh[j] = xv;
        __syncthreads();
        float ar = brj, az = bzj;
        #pragma unroll 8
        for (int k = 0; k < DTOT; ++k) {
            float v = xh[k];
            ar += v * ldw(wrj + k * HIDDEN);
            az += v * ldw(wzj + k * HIDDEN);
        }
        float rg = 1.0f / (1.0f + __expf(-ar));
        float zg = 1.0f / (1.0f + __expf(-az));
        float hj = xh[INPUT + j];
        xrh[INPUT + j] = rg * hj;
        __syncthreads();
        float ah = bhj;
        #pragma unroll 8
        for (int k = 0; k < DTOT; ++k) ah += xrh[k] * ldw(whj + k * HIDDEN);
        float hc = tanhf(ah);
        float hn = zg * hj + (1.0f - zg) * hc;
        xh[INPUT + j] = hn;
        __syncthreads();
    }
    float acc = bo[j];
    #pragma unroll 8
    for (int k = 0; k < HIDDEN; ++k) acc += xh[INPUT + k] * Wo[k * HIDDEN + j];
    out[(size_t)b * HIDDEN + j] = acc;
}

extern "C" void kernel_launch(void* const* d_in, const int* in_sizes, int n_in,
                              void* d_out, int out_size, void* d_ws, size_t ws_size,
                              hipStream_t stream) {
    const float* x  = (const float*)d_in[0];
    const float* Wr = (const float*)d_in[1];
    const float* br = (const float*)d_in[2];
    const float* Wz = (const float*)d_in[3];
    const float* bz = (const float*)d_in[4];
    const float* Wh = (const float*)d_in[5];
    const float* bh = (const float*)d_in[6];
    const float* Wo = (const float*)d_in[7];
    const float* bo = (const float*)d_in[8];
    float* out = (float*)d_out;

    if (ws_size >= WS_NEED_FUSED) {
        unsigned short* ws = (unsigned short*)d_ws;
        (void)hipFuncSetAttribute((const void*)fused_k,
                                  hipFuncAttributeMaxDynamicSharedMemorySize, 66048);
        pack_weights_k<<<224, 256, 0, stream>>>(Wr, Wz, Wh, Wo, ws, 1);
        fused_k<<<256, 512, 66048, stream>>>(x, br, bz, bh, bo, ws, out);
    } else if (ws_size >= WS_NEED_SPLIT) {
        unsigned short* ws = (unsigned short*)d_ws;
        (void)hipFuncSetAttribute((const void*)gru_rec_k,
                                  hipFuncAttributeMaxDynamicSharedMemorySize, 66048);
        pack_weights_k<<<224, 256, 0, stream>>>(Wr, Wz, Wh, Wo, ws, 0);
        xgemm_k<<<256, 512, 0, stream>>>(x, br, bz, bh, ws);
        gru_rec_k<<<16, 512, 66048, stream>>>(bo, ws, out);
    } else if (ws_size >= WS_NEED_OLD) {
        unsigned short* W16 = (unsigned short*)d_ws;
        const size_t n = (size_t)DTOT * HIDDEN;
        prep_weights_k<<<(int)((3 * n + 255) / 256), 256, 0, stream>>>(Wr, Wz, Wh, W16);
        gru_seq_k<unsigned short><<<BATCH, 256, 0, stream>>>(
            x, W16, W16 + n, W16 + 2 * n, br, bz, bh, Wo, bo, out);
    } else {
        gru_seq_k<float><<<BATCH, 256, 0, stream>>>(
            x, Wr, Wz, Wh, br, bz, bh, Wo, bo, out);
    }
}

// Round 9
// 1051.660 us; speedup vs baseline: 2.7233x; 2.7233x over previous
//
#include <hip/hip_runtime.h>
#include <math.h>

// GRU_32564442038643 — round 14: REVERT to R10 split (best verified: 1052us,
// rec 810us).
//  R13 post-mortem: fused producer/consumer = 2800us, all pipes ~1.5% at 20.8%
//  occupancy (everything resident, everything stalled). Mechanism: per-unit
//  __threadfence() at agent scope must write back per-XCD L2 (8 XCDs, L2s not
//  cross-coherent) -> 8400 device-scope flushes thrash L2 (FETCH 100->170MB
//  confirms re-fetch) and serialize the chip. Cross-WG sync cost >> the 150us
//  xgemm overlap it was buying. Column-split rec (512 per-step fences) is dead
//  by the same evidence.
//  Session map: rec floor = serial dep chain (512 steps x 2 phases:
//  bar -> ds_read -> 8-deep MFMA -> transcendental -> write -> bar), pipes
//  <=55%/active-CU. Probes: counted-vmcnt null; conflict-fix -; reg-X -;
//  swap -1% (kept); 1-wave/SIMD -45% (MFMA A/B limited to v0-v255, weights
//  stream from L2; 2-wave TLP covers it); fusion -3.4x. R10 = local optimum
//  of the stream-serialized decomposition.

#define BATCH  256
#define SEQ    512
#define INPUT  256
#define HIDDEN 256
#define DTOT   512
#define NTC    48     // ntc = 6w+s, s:{0,1}=r,{2,3}=z,{4,5}=c, cols (2w+(s&1))*16..
#define NT_O   16
#define LOG2E  1.44269504088896f

typedef float          f32x4 __attribute__((ext_vector_type(4)));
typedef short          s16x8 __attribute__((ext_vector_type(8)));
typedef unsigned short u16x8 __attribute__((ext_vector_type(8)));
typedef unsigned int   u32x2 __attribute__((ext_vector_type(2)));

// ws layout (bytes)
#define WH_OFF   0u            // 393216: h-part weights, ntc frag order, exp2-scaled bf16
#define WX_OFF   393216u       // 393216: x-part, same order
#define WO_OFF   786432u       // 131072: Wo
#define X_OFF    917504u       // 201326592: X[unit][ntc][lane] u32x2, unit = t*16+g
#define WS_NEED     (917504ull + 201326592ull)
#define WS_NEED_OLD 786432ull

__device__ __forceinline__ unsigned short f2bf(float f) {        // RNE
    unsigned int u = __float_as_uint(f);
    u += 0x7FFFu + ((u >> 16) & 1u);
    return (unsigned short)(u >> 16);
}
__device__ __forceinline__ float bf2f(unsigned short u) {
    return __uint_as_float(((unsigned int)u) << 16);
}
__device__ __forceinline__ f32x4 cvt4(u32x2 u) {
    f32x4 a;
    a[0] = __uint_as_float(u[0] << 16);
    a[1] = __uint_as_float(u[0] & 0xffff0000u);
    a[2] = __uint_as_float(u[1] << 16);
    a[3] = __uint_as_float(u[1] & 0xffff0000u);
    return a;
}
__device__ __forceinline__ unsigned int pk2bf(float a, float b) {
    return ((__float_as_uint(a) + 0x8000u) >> 16) |
           ((__float_as_uint(b) + 0x8000u) & 0xFFFF0000u);
}
#if __has_builtin(__builtin_amdgcn_exp2f)
#define EXP2F(x) __builtin_amdgcn_exp2f(x)
#else
#define EXP2F(x) exp2f(x)
#endif
#if __has_builtin(__builtin_amdgcn_rcpf)
#define RCPF(x) __builtin_amdgcn_rcpf(x)
#else
#define RCPF(x) (1.0f / (x))
#endif

#define WAITCNT_VM3()   asm volatile("s_waitcnt vmcnt(3)" ::: "memory")
#define WAITCNT_LGKM0() asm volatile("s_waitcnt lgkmcnt(0)" ::: "memory")
#define BAR() do { __builtin_amdgcn_s_barrier(); __builtin_amdgcn_sched_barrier(0); } while (0)

__device__ __forceinline__ void async_ld16(const void* g, void* l) {
    __builtin_amdgcn_global_load_lds(
        (const __attribute__((address_space(1))) unsigned int*)g,
        (__attribute__((address_space(3))) unsigned int*)l, 16, 0, 0);
}

// ntc -> (gate, col-base)
__device__ __forceinline__ void ntc_decode(int ntc, int& gate, int& colbase) {
    int w = ntc / 6, s = ntc - 6 * w;
    gate = s >> 1;
    colbase = (2 * w + (s & 1)) * 16;
}

// ---------------- weight packing ----------------
// WH/WX frag (ntc,kt), lane l: 8 bf16 = W[k0 + kt*32 + quad*8 + j][colbase + lan]
__global__ __launch_bounds__(256) void pack_weights_k(
    const float* __restrict__ Wr, const float* __restrict__ Wz,
    const float* __restrict__ Wh, const float* __restrict__ Wo,
    unsigned short* __restrict__ ws)
{
    int tid = blockIdx.x * 256 + threadIdx.x;   // 896 tiles * 64
    int tile = tid >> 6;
    int l = tid & 63, quad = l >> 4, lan = l & 15;
    u16x8 v;
    unsigned short* dst;
    if (tile < 768) {
        int isH = tile < 384;
        int t2 = isH ? tile : tile - 384;       // = ntc*8 + kt
        int ntc = t2 >> 3, kt = t2 & 7;
        int gate, colbase;
        ntc_decode(ntc, gate, colbase);
        const float* W = gate == 0 ? Wr : (gate == 1 ? Wz : Wh);
        float scale = (gate == 2) ? 2.f * LOG2E : LOG2E;
        int col = colbase + lan;
        int kbase = (isH ? 256 : 0) + kt * 32 + quad * 8;
        #pragma unroll
        for (int j = 0; j < 8; ++j) v[j] = f2bf(W[(kbase + j) * 256 + col] * scale);
        dst = (unsigned short*)((char*)ws + (isH ? WH_OFF : WX_OFF)) + (size_t)(t2 * 64 + l) * 8;
    } else {
        int t2 = tile - 768;                    // = kt*16 + nt_o
        int kt = t2 / NT_O, nt = t2 % NT_O;
        int col = nt * 16 + lan;
        int kbase = kt * 32 + quad * 8;
        #pragma unroll
        for (int j = 0; j < 8; ++j) v[j] = f2bf(Wo[(kbase + j) * 256 + col]);
        dst = (unsigned short*)((char*)ws + WO_OFF) + (size_t)(t2 * 64 + l) * 8;
    }
    *(u16x8*)dst = v;
}

// ---------------- X precompute (swapped: acc = [batch=lan][col quad*4+r]) -----
// 256 WGs x 512 thr (8 waves, 2/SIMD). Wave w owns ntc 6w..6w+5. Per unit:
// waves register-stage 2 rows of x, pack once to Xbf[16][264], read B-frags
// via ds_read_b128, MFMA with weights as the A operand.
__global__ __launch_bounds__(512, 2) void xgemm_k(
    const float* __restrict__ x,
    const float* __restrict__ br, const float* __restrict__ bz, const float* __restrict__ bh,
    unsigned short* __restrict__ ws)
{
    __shared__ __align__(16) unsigned short Xbf[16][264];
    const int th = threadIdx.x, wave = th >> 6, l = th & 63, quad = l >> 4, lan = l & 15;
    const s16x8* WX = (const s16x8*)((char*)ws + WX_OFF);
    s16x8 wx[6][8];
    #pragma unroll
    for (int fi = 0; fi < 6; ++fi)
        #pragma unroll
        for (int kt = 0; kt < 8; ++kt)
            wx[fi][kt] = WX[(((size_t)(6 * wave + fi)) * 8 + kt) * 64 + l];
    f32x4 bias4[6];                              // bias for cols colbase+quad*4..+3
    #pragma unroll
    for (int fi = 0; fi < 6; ++fi) {
        int gate, colbase;
        ntc_decode(6 * wave + fi, gate, colbase);
        const float* bb = gate == 0 ? br : (gate == 1 ? bz : bh);
        f32x4 bv = *(const f32x4*)&bb[colbase + quad * 4];
        float scale = (gate == 2 ? 2.f * LOG2E : LOG2E);
        bias4[fi][0] = bv[0] * scale; bias4[fi][1] = bv[1] * scale;
        bias4[fi][2] = bv[2] * scale; bias4[fi][3] = bv[3] * scale;
    }
    u32x2* Xout = (u32x2*)((char*)ws + X_OFF);

    f32x4 xs[2];                                 // staged rows {2w, 2w+1}
    {   // prime unit 0
        int unit = blockIdx.x * 32, t = unit >> 4, gg = unit & 15;
        #pragma unroll
        for (int rr = 0; rr < 2; ++rr)
            xs[rr] = *(const f32x4*)(x + (((size_t)(gg * 16 + 2 * wave + rr)) * SEQ + t) * INPUT + l * 4);
    }
    for (int uu = 0; uu < 32; ++uu) {
        if (uu > 0) BAR();                       // prior read phase done; safe to overwrite
        #pragma unroll
        for (int rr = 0; rr < 2; ++rr) {
            u32x2 p;
            p[0] = pk2bf(xs[rr][0], xs[rr][1]);
            p[1] = pk2bf(xs[rr][2], xs[rr][3]);
            *(u32x2*)&Xbf[2 * wave + rr][l * 4] = p;
        }
        if (uu + 1 < 32) {                       // stage next unit into regs
            int unit = blockIdx.x * 32 + uu + 1, t = unit >> 4, gg = unit & 15;
            #pragma unroll
            for (int rr = 0; rr < 2; ++rr)
                xs[rr] = *(const f32x4*)(x + (((size_t)(gg * 16 + 2 * wave + rr)) * SEQ + t) * INPUT + l * 4);
        }
        WAITCNT_LGKM0();                         // Xbf writes visible
        BAR();
        f32x4 acc[6];
        #pragma unroll
        for (int fi = 0; fi < 6; ++fi) acc[fi] = bias4[fi];
        #pragma unroll
        for (int kt = 0; kt < 8; ++kt) {
            s16x8 a = *(const s16x8*)&Xbf[lan][kt * 32 + quad * 8];
            #pragma unroll
            for (int fi = 0; fi < 6; ++fi)
                acc[fi] = __builtin_amdgcn_mfma_f32_16x16x32_bf16(wx[fi][kt], a, acc[fi], 0, 0, 0);
        }
        size_t unit = (size_t)blockIdx.x * 32 + uu;
        #pragma unroll
        for (int fi = 0; fi < 6; ++fi) {
            u32x2 p;
            p[0] = pk2bf(acc[fi][0], acc[fi][1]);
            p[1] = pk2bf(acc[fi][2], acc[fi][3]);
            Xout[(unit * NTC + 6 * wave + fi) * 64 + l] = p;
        }
    }
}

// ---------------- recurrence: 16 WGs x 512 thr (2 waves/SIMD) ----------------
// Swapped-operand structure: thread holds all gate values and h at
// [batch=lan][cols (2w+i)*16+quad*4 .. +3]. r*h, z, h_new in registers;
// Hb/RHb updated with ONE ds_write_b64 per block. Hb/RHb b128 frag reads and
// the X ring (global_load_lds + counted vmcnt(3)) pin a full-step prefetch
// distance in hardware.
__global__ __launch_bounds__(512, 2) void gru_rec_k(
    const float* __restrict__ bo,
    unsigned short* __restrict__ ws,
    float* __restrict__ out)
{
    extern __shared__ __align__(16) char smem[];
    unsigned short (*Hb)[264]  = (unsigned short (*)[264])smem;
    unsigned short (*RHb)[264] = (unsigned short (*)[264])(smem + 8448);
    char* Xr = smem + 16896;                       // [2][8 waves][3072]

    const int th = threadIdx.x, wave = th >> 6, l = th & 63, quad = l >> 4, lan = l & 15;
    const int b = blockIdx.x;
    const s16x8* WH = (const s16x8*)((char*)ws + WH_OFF);
    s16x8 wfr[2][8], wfz[2][8], wfc[2][8];         // 48 frags = 192 regs
    #pragma unroll
    for (int i = 0; i < 2; ++i)
        #pragma unroll
        for (int kt = 0; kt < 8; ++kt) {
            wfr[i][kt] = WH[((6 * wave + i) * 8 + kt) * 64 + l];
            wfz[i][kt] = WH[((6 * wave + 2 + i) * 8 + kt) * 64 + l];
            wfc[i][kt] = WH[((6 * wave + 4 + i) * 8 + kt) * 64 + l];
        }
    for (int idx = th; idx < 16 * 264; idx += 512) ((unsigned short*)Hb)[idx] = 0;
    float h[2][4];                                 // h[batch=lan][(2w+i)*16+quad*4+r]
    #pragma unroll
    for (int i = 0; i < 2; ++i)
        #pragma unroll
        for (int r = 0; r < 4; ++r) h[i][r] = 0.f;

    const char* Xg = (const char*)ws + X_OFF;
    {   // prime t=0 -> buf 0
        const char* sb = Xg + (((size_t)b) * NTC + 6 * wave) * 512;
        char* db = Xr + wave * 3072;
        #pragma unroll
        for (int inst = 0; inst < 3; ++inst)
            async_ld16(sb + inst * 1024 + l * 16, db + inst * 1024);
    }
    __syncthreads();

    for (int t = 0; t < SEQ; ++t) {
        int buf = t & 1;
        {   // prefetch t+1 -> buf^1; stays in flight across both barriers
            int t1 = (t + 1 < SEQ) ? t + 1 : t;
            const char* sb = Xg + (((size_t)(t1 * 16 + b)) * NTC + 6 * wave) * 512;
            char* db = Xr + (buf ^ 1) * 24576 + wave * 3072;
            #pragma unroll
            for (int inst = 0; inst < 3; ++inst)
                async_ld16(sb + inst * 1024 + l * 16, db + inst * 1024);
        }
        WAITCNT_VM3();                             // L(t) landed; L(t+1) in flight
        const char* Xw = Xr + buf * 24576 + wave * 3072;

        // ---- phase A: r,z preacts (swapped: thread = [lan][4 cols]) ----
        f32x4 ar[2], az[2];
        #pragma unroll
        for (int i = 0; i < 2; ++i) {
            ar[i] = cvt4(*(const u32x2*)(Xw + (size_t)i * 512 + l * 8));
            az[i] = cvt4(*(const u32x2*)(Xw + (size_t)(2 + i) * 512 + l * 8));
        }
        #pragma unroll
        for (int kt = 0; kt < 8; ++kt) {
            s16x8 a = *(const s16x8*)&Hb[lan][kt * 32 + quad * 8];
            #pragma unroll
            for (int i = 0; i < 2; ++i) {
                ar[i] = __builtin_amdgcn_mfma_f32_16x16x32_bf16(wfr[i][kt], a, ar[i], 0, 0, 0);
                az[i] = __builtin_amdgcn_mfma_f32_16x16x32_bf16(wfz[i][kt], a, az[i], 0, 0, 0);
            }
        }
        #pragma unroll
        for (int i = 0; i < 2; ++i) {
            int colb = (2 * wave + i) * 16 + quad * 4;
            float rg0 = RCPF(1.f + EXP2F(-ar[i][0]));
            float rg1 = RCPF(1.f + EXP2F(-ar[i][1]));
            float rg2 = RCPF(1.f + EXP2F(-ar[i][2]));
            float rg3 = RCPF(1.f + EXP2F(-ar[i][3]));
            u32x2 rp;
            rp[0] = pk2bf(rg0 * h[i][0], rg1 * h[i][1]);
            rp[1] = pk2bf(rg2 * h[i][2], rg3 * h[i][3]);
            *(u32x2*)&RHb[lan][colb] = rp;         // one ds_write_b64
        }
        WAITCNT_LGKM0();                           // RHb writes visible
        BAR();

        // zg in regs; overlaps phase-B LDS-read/MFMA latency.
        float zg[2][4];
        #pragma unroll
        for (int i = 0; i < 2; ++i)
            #pragma unroll
            for (int r = 0; r < 4; ++r)
                zg[i][r] = RCPF(1.f + EXP2F(-az[i][r]));

        // ---- phase B: candidate ----
        f32x4 ac[2];
        #pragma unroll
        for (int i = 0; i < 2; ++i)
            ac[i] = cvt4(*(const u32x2*)(Xw + (size_t)(4 + i) * 512 + l * 8));
        #pragma unroll
        for (int kt = 0; kt < 8; ++kt) {
            s16x8 a = *(const s16x8*)&RHb[lan][kt * 32 + quad * 8];
            #pragma unroll
            for (int i = 0; i < 2; ++i)
                ac[i] = __builtin_amdgcn_mfma_f32_16x16x32_bf16(wfc[i][kt], a, ac[i], 0, 0, 0);
        }
        #pragma unroll
        for (int i = 0; i < 2; ++i) {
            int colb = (2 * wave + i) * 16 + quad * 4;
            #pragma unroll
            for (int r = 0; r < 4; ++r) {
                float e  = EXP2F(ac[i][r]);              // exp(2*preact)
                float hc = (e - 1.f) * RCPF(e + 1.f);    // tanh
                h[i][r] = zg[i][r] * (h[i][r] - hc) + hc;
            }
            u32x2 hp;
            hp[0] = pk2bf(h[i][0], h[i][1]);
            hp[1] = pk2bf(h[i][2], h[i][3]);
            *(u32x2*)&Hb[lan][colb] = hp;          // one ds_write_b64
        }
        WAITCNT_LGKM0();                           // Hb writes visible
        BAR();
    }

    // ---- epilogue: out = h_last @ Wo + bo (swapped; dwordx4 stores) ----
    const s16x8* WO = (const s16x8*)((char*)ws + WO_OFF);
    #pragma unroll
    for (int i = 0; i < 2; ++i) {
        int nt = 2 * wave + i;
        f32x4 acc = *(const f32x4*)&bo[nt * 16 + quad * 4];
        #pragma unroll
        for (int kt = 0; kt < 8; ++kt) {
            s16x8 a = *(const s16x8*)&Hb[lan][kt * 32 + quad * 8];
            acc = __builtin_amdgcn_mfma_f32_16x16x32_bf16(WO[(kt * NT_O + nt) * 64 + l], a, acc, 0, 0, 0);
        }
        *(f32x4*)&out[(size_t)(b * 16 + lan) * 256 + nt * 16 + quad * 4] = acc;
    }
}

// ---------------- fallbacks (ws too small) ----------------
__global__ __launch_bounds__(256) void prep_weights_k(
    const float* __restrict__ Wr, const float* __restrict__ Wz,
    const float* __restrict__ Wh, unsigned short* __restrict__ W16)
{
    const int n = DTOT * HIDDEN;
    int idx = blockIdx.x * 256 + threadIdx.x;
    if (idx >= 3 * n) return;
    int m = idx / n;
    int r = idx - m * n;
    const float* src = (m == 0) ? Wr : ((m == 1) ? Wz : Wh);
    W16[idx] = f2bf(src[r]);
}
__device__ __forceinline__ float ldw(const unsigned short* p) { return bf2f(*p); }
__device__ __forceinline__ float ldw(const float* p)          { return *p; }

template <typename WT>
__global__ __launch_bounds__(256) void gru_seq_k(
    const float* __restrict__ x,
    const WT* __restrict__ Wr, const WT* __restrict__ Wz, const WT* __restrict__ Wh,
    const float* __restrict__ br, const float* __restrict__ bz, const float* __restrict__ bh,
    const float* __restrict__ Wo, const float* __restrict__ bo,
    float* __restrict__ out)
{
    const int b = blockIdx.x, j = threadIdx.x;
    __shared__ float xh[DTOT];
    __shared__ float xrh[DTOT];
    xh[INPUT + j] = 0.0f;
    const float brj = br[j], bzj = bz[j], bhj = bh[j];
    const float* xb = x + (size_t)b * SEQ * INPUT;
    const WT* wrj = Wr + j;
    const WT* wzj = Wz + j;
    const WT* whj = Wh + j;
    __syncthreads();
    for (int t = 0; t < SEQ; ++t) {
        float xv = xb[t * INPUT + j];
        xh[j] = xv; xrh[j] = xv;
        __syncthreads();
        float ar = brj, az = bzj;
        #pragma unroll 8
        for (int k = 0; k < DTOT; ++k) {
            float v = xh[k];
            ar += v * ldw(wrj + k * HIDDEN);
            az += v * ldw(wzj + k * HIDDEN);
        }
        float rg = 1.0f / (1.0f + __expf(-ar));
        float zg = 1.0f / (1.0f + __expf(-az));
        float hj = xh[INPUT + j];
        xrh[INPUT + j] = rg * hj;
        __syncthreads();
        float ah = bhj;
        #pragma unroll 8
        for (int k = 0; k < DTOT; ++k) ah += xrh[k] * ldw(whj + k * HIDDEN);
        float hc = tanhf(ah);
        float hn = zg * hj + (1.0f - zg) * hc;
        xh[INPUT + j] = hn;
        __syncthreads();
    }
    float acc = bo[j];
    #pragma unroll 8
    for (int k = 0; k < HIDDEN; ++k) acc += xh[INPUT + k] * Wo[k * HIDDEN + j];
    out[(size_t)b * HIDDEN + j] = acc;
}

extern "C" void kernel_launch(void* const* d_in, const int* in_sizes, int n_in,
                              void* d_out, int out_size, void* d_ws, size_t ws_size,
                              hipStream_t stream) {
    const float* x  = (const float*)d_in[0];
    const float* Wr = (const float*)d_in[1];
    const float* br = (const float*)d_in[2];
    const float* Wz = (const float*)d_in[3];
    const float* bz = (const float*)d_in[4];
    const float* Wh = (const float*)d_in[5];
    const float* bh = (const float*)d_in[6];
    const float* Wo = (const float*)d_in[7];
    const float* bo = (const float*)d_in[8];
    float* out = (float*)d_out;

    if (ws_size >= WS_NEED) {
        unsigned short* ws = (unsigned short*)d_ws;
        (void)hipFuncSetAttribute((const void*)gru_rec_k,
                                  hipFuncAttributeMaxDynamicSharedMemorySize, 66048);
        pack_weights_k<<<224, 256, 0, stream>>>(Wr, Wz, Wh, Wo, ws);
        xgemm_k<<<256, 512, 0, stream>>>(x, br, bz, bh, ws);
        gru_rec_k<<<16, 512, 66048, stream>>>(bo, ws, out);
    } else if (ws_size >= WS_NEED_OLD) {
        unsigned short* W16 = (unsigned short*)d_ws;
        const size_t n = (size_t)DTOT * HIDDEN;
        prep_weights_k<<<(int)((3 * n + 255) / 256), 256, 0, stream>>>(Wr, Wz, Wh, W16);
        gru_seq_k<unsigned short><<<BATCH, 256, 0, stream>>>(
            x, W16, W16 + n, W16 + 2 * n, br, bz, bh, Wo, bo, out);
    } else {
        gru_seq_k<float><<<BATCH, 256, 0, stream>>>(
            x, Wr, Wz, Wh, br, bz, bh, Wo, bo, out);
    }
}